// Round 8
// baseline (160.570 us; speedup 1.0000x reference)
//
#include <hip/hip_runtime.h>
#include <stdint.h>

// B=8, C=256, Nl=4096 (64x64), Nh=1024 (32x32), qd=64.
// kvprep (384 blocks): bid<128: K = Wk@high+bk -> kws [b][1024h][64qd] bf16,
//   row-XOR ((h&7)<<4); bid>=128: V = bf16(high) -> vws [b][32ck][256c][32h],
//   row-XOR ((c&3)<<4).
// attn (1024 blocks = b x 32-l tile, 4 waves, LDS 40960 = 4 blocks/CU):
//   Phase 1: Q-prep of own tile via MFMA -> Q^T B-fragments in registers.
//   Phase 2: 32 chunks of 32 h, ONE barrier per chunk:
//     swapped QK: S^T = mfma(K_A, Q^T_B) -> lane holds P column l=lcol
//     exp in-reg, pack bf16, 8-shfl redistribution -> PV B-frag (P never in LDS)
//     swapped PV: O^T += mfma(V^T_A, P^T_B); rowsum = per-lane scalar.
//   Epilogue: out = low + gamma * O^T / rowsum (per-lane scalar inv).

#define APAD 40

typedef __attribute__((ext_vector_type(8))) short bf16x8;
typedef __attribute__((ext_vector_type(4))) float f32x4;

typedef const __attribute__((address_space(1))) uint32_t* gp1_t;
typedef __attribute__((address_space(3))) uint32_t* sp3_t;

__device__ __forceinline__ uint32_t f2bf(float f) {
    uint32_t u = __builtin_bit_cast(uint32_t, f);
    return (u + 0x7FFFu + ((u >> 16) & 1u)) >> 16;   // RNE f32->bf16
}
__device__ __forceinline__ uint32_t pk2(float a, float b) {
    return f2bf(a) | (f2bf(b) << 16);
}
__device__ __forceinline__ void async16(void* lds, const void* g) {
    __builtin_amdgcn_global_load_lds((gp1_t)g, (sp3_t)lds, 16, 0, 0);
}

union U8 { uint16_t u[8]; bf16x8 v; };
__device__ __forceinline__ bf16x8 pack8(const float* f) {
    U8 t;
#pragma unroll
    for (int i = 0; i < 8; ++i) t.u[i] = (uint16_t)f2bf(f[i]);
    return t.v;
}

// ---------------------------------------------------------------------------
// kvprep: K-projection + V-cast (small, 384 blocks)
// ---------------------------------------------------------------------------
__global__ __launch_bounds__(256) void kvprep(
    const float* __restrict__ high,
    const float* __restrict__ Wk, const float* __restrict__ bk,
    uint16_t* __restrict__ kws, uint16_t* __restrict__ vws)
{
    __shared__ uint16_t Alds[2 * 64 * APAD];
    int bid = blockIdx.x, tid = threadIdx.x;

    if (bid >= 128) {                       // ---- V-cast (256 blocks) ----
        int v = bid - 128;
#pragma unroll
        for (int it = 0; it < 4; ++it) {
            int t = it * 65536 + v * 256 + tid;   // 262144 total, 8 h each
            int row = t >> 7, seg = t & 127;      // row = b*256+c
            int vb = row >> 8, c = row & 255;
            int h0 = seg << 3;
            const float* src = high + ((size_t)row << 10) + h0;
            float4 a = *(const float4*)src;
            float4 d = *(const float4*)(src + 4);
            uint4 val;
            val.x = pk2(a.x, a.y);
            val.y = pk2(a.z, a.w);
            val.z = pk2(d.x, d.y);
            val.w = pk2(d.z, d.w);
            int ck = h0 >> 5, hl = h0 & 31;       // 32 chunks of 32 h
            *(uint4*)((char*)vws +
                ((size_t)((vb * 32 + ck) * 256 + c)) * 64 +
                (size_t)((hl * 2) ^ ((c & 3) << 4))) = val;
        }
        return;
    }

    // ---- K GEMM: M=64 h, N=64 qd, K=256 c per block ----
    int kb = bid >> 4, hb = bid & 15;
    const float* X = high + ((size_t)kb << 18) + hb * 64;
    int w = tid >> 6, lane = tid & 63, g = lane >> 4, lcol = lane & 15;
    int p = tid >> 4, lg = tid & 15;
    int qd = w * 16 + lcol;
    f32x4 acc[4];
#pragma unroll
    for (int i = 0; i < 4; ++i) acc[i] = (f32x4){0.f, 0.f, 0.f, 0.f};
#pragma unroll 1
    for (int cs = 0; cs < 8; ++cs) {
        int c0 = cs * 32;
        uint16_t* Ab = Alds + (cs & 1) * (64 * APAD);
        const float* r0 = X + (size_t)(c0 + p * 2) * 1024 + lg * 4;
        float4 x0 = *(const float4*)r0;
        float4 x1 = *(const float4*)(r0 + 1024);
        const float* wr = Wk + qd * 256 + c0 + g * 8;
        float4 wa = *(const float4*)wr;
        float4 wb = *(const float4*)(wr + 4);
        const float* px0 = (const float*)&x0;
        const float* px1 = (const float*)&x1;
#pragma unroll
        for (int j = 0; j < 4; ++j)
            *(uint32_t*)&Ab[(lg * 4 + j) * APAD + p * 2] = pk2(px0[j], px1[j]);
        __syncthreads();
        float wf[8] = {wa.x, wa.y, wa.z, wa.w, wb.x, wb.y, wb.z, wb.w};
        bf16x8 bfrag = pack8(wf);
#pragma unroll
        for (int mt = 0; mt < 4; ++mt) {
            bf16x8 af = *(const bf16x8*)&Ab[(mt * 16 + lcol) * APAD + g * 8];
            acc[mt] = __builtin_amdgcn_mfma_f32_16x16x32_bf16(af, bfrag, acc[mt], 0, 0, 0);
        }
    }
    float bkv = bk[qd];
    char* kdst = (char*)kws + (size_t)(kb * 1024 + hb * 64) * 128;
#pragma unroll
    for (int mt = 0; mt < 4; ++mt)
#pragma unroll
        for (int r = 0; r < 4; ++r) {
            int hl = mt * 16 + g * 4 + r;
            *(uint16_t*)(kdst + hl * 128 + (((qd * 2) ^ ((hl & 7) << 4)))) =
                (uint16_t)f2bf(acc[mt][r] + bkv);
        }
}

// ---------------------------------------------------------------------------
// attn
// ---------------------------------------------------------------------------
__global__ __launch_bounds__(256, 4) void attn(
    const float* __restrict__ low, const float* __restrict__ Wq,
    const float* __restrict__ bq, const float* __restrict__ gamma_p,
    const uint16_t* __restrict__ kws, const uint16_t* __restrict__ vws,
    float* __restrict__ out)
{
    __shared__ char smem[40960];
    char* Vc = smem;                        // 2 x [256c][32h] bf16 = 32 KB
    char* Kc = smem + 32768;                // 2 x [32h][64qd] bf16 = 8 KB
    // Phase-1 overlays (inside Vc buf0, dead before staging):
    uint16_t* Alds = (uint16_t*)smem;       // dbuf 2 x [32][APAD] = 5120 B
    char* Qlds = smem + 8192;               // [32l][64qd] bf16 swizzled, 4 KB

    int bid = blockIdx.x;
    int blk = (bid & 7) * 128 + (bid >> 3); // XCD swizzle (bijective: 1024%8==0)
    int b = blk >> 7;
    int l0 = (blk & 127) * 32;
    int tid = threadIdx.x, w = tid >> 6, lane = tid & 63;
    int g = lane >> 4, lcol = lane & 15;
    int wl = w & 1, wc = w >> 1;            // wave = (l-half, c-half)

    const float* lowb = low + ((size_t)b << 20);
    int qd = w * 16 + lcol;

    // ================= Phase 1: Q-prep (own 32-l tile) =================
    f32x4 qacc[2];
    qacc[0] = (f32x4){0.f, 0.f, 0.f, 0.f};
    qacc[1] = (f32x4){0.f, 0.f, 0.f, 0.f};
    {
        int cpair = tid >> 3, lseg = tid & 7;       // tid<128 stage A
#pragma unroll 1
        for (int cs = 0; cs < 8; ++cs) {
            int c0 = cs * 32;
            uint16_t* Ab = Alds + (cs & 1) * (32 * APAD);
            if (tid < 128) {
                const float* r0 = lowb + (size_t)(c0 + cpair * 2) * 4096 + l0 + lseg * 4;
                float4 x0 = *(const float4*)r0;
                float4 x1 = *(const float4*)(r0 + 4096);
                const float* px0 = (const float*)&x0;
                const float* px1 = (const float*)&x1;
#pragma unroll
                for (int j = 0; j < 4; ++j)
                    *(uint32_t*)&Ab[(lseg * 4 + j) * APAD + cpair * 2] =
                        pk2(px0[j], px1[j]);
            }
            const float* wr = Wq + qd * 256 + c0 + g * 8;
            float4 wa = *(const float4*)wr;
            float4 wb = *(const float4*)(wr + 4);
            __syncthreads();                // dbuf: 1 barrier per cs
            float wf[8] = {wa.x, wa.y, wa.z, wa.w, wb.x, wb.y, wb.z, wb.w};
            bf16x8 bfrag = pack8(wf);
#pragma unroll
            for (int mt = 0; mt < 2; ++mt) {
                bf16x8 af = *(const bf16x8*)&Ab[(mt * 16 + lcol) * APAD + g * 8];
                qacc[mt] = __builtin_amdgcn_mfma_f32_16x16x32_bf16(af, bfrag, qacc[mt], 0, 0, 0);
            }
        }
    }
    {   // +bq, exchange through swizzled Qlds (producer layout: col qd per wave)
        float bqv = bq[qd];
#pragma unroll
        for (int mt = 0; mt < 2; ++mt)
#pragma unroll
            for (int r = 0; r < 4; ++r) {
                int l = mt * 16 + g * 4 + r;
                *(uint16_t*)(Qlds + l * 128 + (((qd * 2) ^ ((l & 7) << 4)))) =
                    (uint16_t)f2bf(qacc[mt][r] + bqv);
            }
    }
    __syncthreads();
    // Q^T B-fragments: lane holds col l = wl*16+lcol, k = qd = kp*32+g*8+j
    bf16x8 qB[2];
    {
        int lq = wl * 16 + lcol;
#pragma unroll
        for (int kp = 0; kp < 2; ++kp)
            qB[kp] = *(const bf16x8*)(Qlds + lq * 128 +
                      (((kp * 64 + g * 16) ^ ((lq & 7) << 4))));
    }
    __syncthreads();                        // Qlds/Alds dead; Vc reusable

    // ================= Phase 2 =================
    const char* Kb = (const char*)kws + (size_t)b * 131072;
    const char* Vb = (const char*)vws + (size_t)b * 524288;

#define STAGE(ck, bf_)                                                        \
    {                                                                         \
        const char* vg_ = Vb + (ck) * 16384;                                  \
        const char* kg_ = Kb + (ck) * 4096;                                   \
        char* vl_ = Vc + (bf_) * 16384;                                       \
        char* kl_ = Kc + (bf_) * 4096;                                        \
        _Pragma("unroll")                                                     \
        for (int r_ = 0; r_ < 5; ++r_) {                                      \
            int s_ = r_ * 4 + w;                                              \
            if (s_ < 16) async16(vl_ + s_ * 1024, vg_ + s_ * 1024 + lane * 16);\
            else async16(kl_ + (s_ - 16) * 1024, kg_ + (s_ - 16) * 1024 + lane * 16);\
        }                                                                     \
    }

    STAGE(0, 0);
    asm volatile("s_waitcnt vmcnt(0)" ::: "memory");
    __builtin_amdgcn_sched_barrier(0);
    __builtin_amdgcn_s_barrier();

    f32x4 oacc[8];
#pragma unroll
    for (int i = 0; i < 8; ++i) oacc[i] = (f32x4){0.f, 0.f, 0.f, 0.f};
    float rowp = 0.f;
    int sl0 = ((g & 1) << 5) + lcol;        // shfl source lanes for the P dance
    int sl1 = sl0 + 16;
    bool hiG = (g >= 2);

#pragma unroll 1
    for (int ck = 0; ck < 32; ++ck) {
        int buf = ck & 1;
        if (ck + 1 < 32) STAGE(ck + 1, buf ^ 1);   // readers of buf^1 passed last barrier

        // --- swapped QK: S^T[h][l], lane holds l=wl*16+lcol, h=4g+r (+16) ---
        const char* kl = Kc + buf * 4096;
        f32x4 sacc0 = (f32x4){0.f, 0.f, 0.f, 0.f};
        f32x4 sacc1 = (f32x4){0.f, 0.f, 0.f, 0.f};
#pragma unroll
        for (int kp = 0; kp < 2; ++kp) {
            bf16x8 ka0 = *(const bf16x8*)(kl + lcol * 128 +
                           (((kp * 64 + g * 16) ^ ((lcol & 7) << 4))));
            sacc0 = __builtin_amdgcn_mfma_f32_16x16x32_bf16(ka0, qB[kp], sacc0, 0, 0, 0);
            int h1 = 16 + lcol;
            bf16x8 ka1 = *(const bf16x8*)(kl + h1 * 128 +
                           (((kp * 64 + g * 16) ^ ((h1 & 7) << 4))));
            sacc1 = __builtin_amdgcn_mfma_f32_16x16x32_bf16(ka1, qB[kp], sacc1, 0, 0, 0);
        }

        // --- P = exp(S) in registers; build PV B-frag via 8 shfl ---
        float e0[4], e1[4];
#pragma unroll
        for (int r = 0; r < 4; ++r) { e0[r] = __expf(sacc0[r]); e1[r] = __expf(sacc1[r]); }
        rowp += (e0[0] + e0[1]) + (e0[2] + e0[3]) + (e1[0] + e1[1]) + (e1[2] + e1[3]);
        uint32_t pAx = pk2(e0[0], e0[1]), pAy = pk2(e0[2], e0[3]);
        uint32_t pBx = pk2(e1[0], e1[1]), pBy = pk2(e1[2], e1[3]);
        uint32_t a0 = (uint32_t)__shfl((int)pAx, sl0, 64);
        uint32_t a1 = (uint32_t)__shfl((int)pAy, sl0, 64);
        uint32_t a2 = (uint32_t)__shfl((int)pAx, sl1, 64);
        uint32_t a3 = (uint32_t)__shfl((int)pAy, sl1, 64);
        uint32_t b0 = (uint32_t)__shfl((int)pBx, sl0, 64);
        uint32_t b1 = (uint32_t)__shfl((int)pBy, sl0, 64);
        uint32_t b2 = (uint32_t)__shfl((int)pBx, sl1, 64);
        uint32_t b3 = (uint32_t)__shfl((int)pBy, sl1, 64);
        uint4 pw;
        pw.x = hiG ? b0 : a0;
        pw.y = hiG ? b1 : a1;
        pw.z = hiG ? b2 : a2;
        pw.w = hiG ? b3 : a3;
        bf16x8 pfrag = __builtin_bit_cast(bf16x8, pw);

        // --- swapped PV: O^T[c][l] += V^T[c][h] * P^T[h][l] ---
        const char* vl = Vc + buf * 16384;
#pragma unroll
        for (int ct = 0; ct < 8; ++ct) {
            int c = wc * 128 + ct * 16 + lcol;
            bf16x8 va = *(const bf16x8*)(vl + c * 64 + (((g * 16) ^ ((c & 3) << 4))));
            oacc[ct] = __builtin_amdgcn_mfma_f32_16x16x32_bf16(va, pfrag, oacc[ct], 0, 0, 0);
        }

        if (ck + 1 < 32) {
            asm volatile("s_waitcnt vmcnt(0)" ::: "memory");   // next-chunk stage landed
            __builtin_amdgcn_sched_barrier(0);
            __builtin_amdgcn_s_barrier();   // ONE barrier per chunk
        }
    }

    // rowsum: complete per-l sum across g-groups (lane-local l = wl*16+lcol)
    rowp += __shfl_xor(rowp, 16, 64);
    rowp += __shfl_xor(rowp, 32, 64);
    float inv = gamma_p[0] / rowp;

    // epilogue: out = low + gamma * O^T / rowsum
    int l = l0 + wl * 16 + lcol;
#pragma unroll
    for (int ct = 0; ct < 8; ++ct) {
#pragma unroll
        for (int r = 0; r < 4; ++r) {
            int c = wc * 128 + ct * 16 + g * 4 + r;
            size_t idx = ((size_t)(b * 256 + c) << 12) + l;
            out[idx] = low[idx] + oacc[ct][r] * inv;
        }
    }
}

// ---------------------------------------------------------------------------
extern "C" void kernel_launch(void* const* d_in, const int* in_sizes, int n_in,
                              void* d_out, int out_size, void* d_ws, size_t ws_size,
                              hipStream_t stream) {
    const float* low   = (const float*)d_in[0];
    const float* high  = (const float*)d_in[1];
    const float* Wq    = (const float*)d_in[2];
    const float* bq    = (const float*)d_in[3];
    const float* Wk    = (const float*)d_in[4];
    const float* bk    = (const float*)d_in[5];
    const float* gamma = (const float*)d_in[6];
    float* out = (float*)d_out;

    uint16_t* kws = (uint16_t*)d_ws;                         // 1 MB
    uint16_t* vws = (uint16_t*)((char*)d_ws + (1u << 20));   // 4 MB

    kvprep<<<dim3(384), dim3(256), 0, stream>>>(high, Wk, bk, kws, vws);
    attn<<<dim3(1024), dim3(256), 0, stream>>>(low, Wq, bq, gamma, kws, vws, out);
}